// Round 7
// baseline (284.314 us; speedup 1.0000x reference)
//
#include <hip/hip_runtime.h>
#include <stdint.h>

// GraphConvLayer: 3x { x = X@W^T + b; x = Ahat @ x; x *= mask; x = gelu(x) }
// B=32, N=1024, D=256. Split-bf16 (hi/lo) MFMA for f32-grade accuracy.
// R7 = R6 with compile fix: NT builtins need ext_vector_type, not HIP_vector_type.
//   A-stream GLD loads NT (keep Y L2-resident), epilogue stores NT,
//   k_norm_adj fully NT. k_agg structure unchanged from R5.
// Tiled layouts (bf16, 16B-aligned):
//   An : [b][mb=node/128][kt=k/32][row 128][32]   tile stride 4096 elems
//   Yt : [b][kt=node/32][feat 256][32]            tile stride 8192 elems

typedef __attribute__((ext_vector_type(8))) short short8;   // 8 bf16 (4 VGPRs)
typedef __attribute__((ext_vector_type(4))) float f32x4;    // MFMA acc
typedef __attribute__((ext_vector_type(4))) float fv4;      // NT-loadable float4
typedef __attribute__((ext_vector_type(4))) unsigned short u16x4;  // NT-storable ushort4

__device__ __forceinline__ uint16_t f2bf(float f) {
  uint32_t u = __float_as_uint(f);
  u += 0x7FFF + ((u >> 16) & 1);          // RNE
  return (uint16_t)(u >> 16);
}
__device__ __forceinline__ float bf2f(uint16_t h) {
  return __uint_as_float(((uint32_t)h) << 16);
}
__device__ __forceinline__ float gelu_exact(float v) {
  return 0.5f * v * (1.0f + erff(v * 0.70710678118654752f));
}
__device__ __forceinline__ f32x4 mfma16(short8 a, short8 b, f32x4 c) {
  return __builtin_amdgcn_mfma_f32_16x16x32_bf16(a, b, c, 0, 0, 0);
}

#define GLD16(gsrc, ldst) __builtin_amdgcn_global_load_lds(                    \
    (const __attribute__((address_space(1))) void*)(gsrc),                     \
    (__attribute__((address_space(3))) void*)(ldst), 16, 0, 0)
// NT variant: aux bit1 = NT (non-temporal) on gfx950 — streaming, evict-first.
#define GLD16NT(gsrc, ldst) __builtin_amdgcn_global_load_lds(                  \
    (const __attribute__((address_space(1))) void*)(gsrc),                     \
    (__attribute__((address_space(3))) void*)(ldst), 16, 0, 2)

// ---------------- split f32 -> bf16 hi/lo ----------------
__global__ void k_split(const float* __restrict__ src, uint16_t* __restrict__ h,
                        uint16_t* __restrict__ l, int n4) {
  int i = blockIdx.x * blockDim.x + threadIdx.x;
  if (i >= n4) return;
  const fv4 v = __builtin_nontemporal_load(((const fv4*)src) + i);
  float vv[4] = {v.x, v.y, v.z, v.w};
  ushort4 hh, ll;
  uint16_t* hp = (uint16_t*)&hh;
  uint16_t* lp = (uint16_t*)&ll;
#pragma unroll
  for (int e = 0; e < 4; ++e) {
    uint16_t hb = f2bf(vv[e]);
    hp[e] = hb;
    lp[e] = f2bf(vv[e] - bf2f(hb));
  }
  ((ushort4*)h)[i] = hh;
  ((ushort4*)l)[i] = ll;
}

// ---------------- row-normalize adj -> bf16, TILED store, fully NT ----------------
__global__ void k_norm_adj(const float* __restrict__ adj, uint16_t* __restrict__ An) {
  const int r = blockIdx.x;       // 0..32767 = b*1024 + node
  const int t = threadIdx.x;      // 0..255, handles k = t*4 .. t*4+3
  const float* row = adj + (size_t)r * 1024;
  const fv4 v = __builtin_nontemporal_load((const fv4*)(row + t * 4));
  float s = v.x + v.y + v.z + v.w;
#pragma unroll
  for (int off = 32; off; off >>= 1) s += __shfl_down(s, off);
  __shared__ float ws[4];
  if ((t & 63) == 0) ws[t >> 6] = s;
  __syncthreads();
  const float deg = ws[0] + ws[1] + ws[2] + ws[3];
  const float dinv = (deg != 0.f) ? 1.f / deg : 0.f;
  u16x4 o;
  float vv[4] = {v.x, v.y, v.z, v.w};
#pragma unroll
  for (int e = 0; e < 4; ++e) o[e] = f2bf(vv[e] * dinv);
  // tiled: [b][mb][kt][row 128][32]
  const int b = r >> 10, node = r & 1023;
  const int mb = node >> 7, rr = node & 127;
  const int kt = t >> 3, ko = (t * 4) & 31;
  const size_t oo = (size_t)(b * 8 + mb) * 131072 + kt * 4096 + rr * 32 + ko;
  __builtin_nontemporal_store(o, (u16x4*)(An + oo));
}

// ---------------- linear: Yt = (X @ W^T + b), split, TILED store ----------------
__global__ __launch_bounds__(256) void k_linear(
    const uint16_t* __restrict__ Xh, const uint16_t* __restrict__ Xl,
    const uint16_t* __restrict__ Wh, const uint16_t* __restrict__ Wl,
    const float* __restrict__ bias,
    uint16_t* __restrict__ Yth, uint16_t* __restrict__ Ytl) {
  __shared__ __align__(16) uint8_t smem[32768];  // Ah|Al|Wh|Wl tiles, 8KB each
  const int tid = threadIdx.x;
  const int lane = tid & 63;
  const int wave = tid >> 6;
  const int wr = wave >> 1, wc = wave & 1;
  const int m0 = blockIdx.x * 128;   // global row (b*1024+node)
  const int n0 = blockIdx.y * 128;   // out-feature
  const int lm = lane & 15, g = lane >> 4;
  const int srow = lane >> 2;
  const int skof = (lane & 3) * 8;

  f32x4 acc[4][4] = {};

  for (int kt = 0; kt < 8; ++kt) {
    const int k0 = kt * 32;
    __syncthreads();
#pragma unroll
    for (int j = 0; j < 8; ++j) {
      const int c = j * 4 + wave;    // 0..31
      const int sub = c & 7, which = c >> 3;
      const int row = sub * 16 + srow;
      const uint16_t* src;
      if (which == 0)      src = Xh + (size_t)(m0 + row) * 256 + k0 + skof;
      else if (which == 1) src = Xl + (size_t)(m0 + row) * 256 + k0 + skof;
      else if (which == 2) src = Wh + (size_t)(n0 + row) * 256 + k0 + skof;
      else                 src = Wl + (size_t)(n0 + row) * 256 + k0 + skof;
      GLD16(src, smem + c * 1024);
    }
    asm volatile("s_waitcnt vmcnt(0)" ::: "memory");
    __syncthreads();

    const uint8_t* Ahs = smem;
    const uint8_t* Als = smem + 8192;
    const uint8_t* Bhs = smem + 16384;
    const uint8_t* Bls = smem + 24576;
    short8 ah[4], al[4], bh[4], bl[4];
#pragma unroll
    for (int f = 0; f < 4; ++f) {
      ah[f] = *(const short8*)(Ahs + (wr * 64 + f * 16 + lm) * 64 + g * 16);
      al[f] = *(const short8*)(Als + (wr * 64 + f * 16 + lm) * 64 + g * 16);
      bh[f] = *(const short8*)(Bhs + (wc * 64 + f * 16 + lm) * 64 + g * 16);
      bl[f] = *(const short8*)(Bls + (wc * 64 + f * 16 + lm) * 64 + g * 16);
    }
#pragma unroll
    for (int fm = 0; fm < 4; ++fm)
#pragma unroll
      for (int fn = 0; fn < 4; ++fn) {
        acc[fm][fn] = mfma16(ah[fm], bh[fn], acc[fm][fn]);
        acc[fm][fn] = mfma16(ah[fm], bl[fn], acc[fm][fn]);
        acc[fm][fn] = mfma16(al[fm], bh[fn], acc[fm][fn]);
      }
  }

  // epilogue: +bias, hi/lo split, store TILED [b][kt][feat][32]
#pragma unroll
  for (int fn = 0; fn < 4; ++fn) {
    const int n = n0 + wc * 64 + fn * 16 + lm;
    const float bv = bias[n];
#pragma unroll
    for (int fm = 0; fm < 4; ++fm) {
      const int mg = m0 + wr * 64 + fm * 16 + g * 4;
      const int bb = mg >> 10, node = mg & 1023;
      const int kt = node >> 5, ko = node & 31;
      ushort4 hh, ll;
      uint16_t* hp = (uint16_t*)&hh;
      uint16_t* lp = (uint16_t*)&ll;
#pragma unroll
      for (int e = 0; e < 4; ++e) {
        const float v = acc[fm][fn][e] + bv;
        const uint16_t hb = f2bf(v);
        hp[e] = hb;
        lp[e] = f2bf(v - bf2f(hb));
      }
      const size_t o = ((size_t)(bb * 32 + kt) * 256 + n) * 32 + ko;
      *(ushort4*)(Yth + o) = hh;
      *(ushort4*)(Ytl + o) = ll;
    }
  }
}

// ---------------- aggregate: Z = An[b] @ Y, mask, gelu ----------------
// Tile 128(M) x 256(N) x 32(K), 32 K-tiles. 8 waves (2M x 4N), wave 64x64.
// GLD-staged 3-tile LDS ring [A 8K | Bh 16K | Bl 16K]=40960B per slot.
// Per tile: vmcnt(5) (counted) + 1 raw s_barrier; stage t+2 post-barrier.
// A loads are NT (use-once stream); Y loads default (L2-resident reuse).
#define STAGE(T, SSL) {                                                        \
    const size_t ta_ = (size_t)(T) * 4096;                                     \
    const size_t tb_ = (size_t)(T) * 8192;                                     \
    uint8_t* d_ = smem + (SSL) + wofs;                                         \
    GLD16NT(gA + ta_,      d_);                                                \
    GLD16(gH + tb_,        d_ + 8192);                                         \
    GLD16(gH + tb_ + 4096, d_ + 16384);                                        \
    GLD16(gL + tb_,        d_ + 24576);                                        \
    GLD16(gL + tb_ + 4096, d_ + 32768);                                        \
  }

template <bool LAST>
__global__ __launch_bounds__(512, 1) void k_agg(
    const uint16_t* __restrict__ An,
    const uint16_t* __restrict__ Yth, const uint16_t* __restrict__ Ytl,
    const float* __restrict__ mask,
    uint16_t* __restrict__ Xh, uint16_t* __restrict__ Xl,
    float* __restrict__ out) {
  __shared__ __align__(16) uint8_t smem[122880];   // 3 x 40960 ring
  const int tid = threadIdx.x;
  const int lane = tid & 63;
  const int wave = tid >> 6;            // 0..7
  const int wr = wave >> 2, wc = wave & 3;        // 2(M) x 4(N)
  const int id = blockIdx.x;            // 0..255
  const int swz = (id & 7) * 32 + (id >> 3);      // XCD-chunked (bijective)
  const int b = swz >> 3;               // batch
  const int mb = swz & 7;               // node block (of 128)
  const int lm = lane & 15, g = lane >> 4;
  const int wofs = wave * 1024;         // wave-uniform staging dst offset

  // per-thread staging sources (tiled layouts are GLD-linear)
  const uint16_t* gA = An  + (size_t)(b * 8 + mb) * 131072 + tid * 8;
  const uint16_t* gH = Yth + (size_t)b * 262144 + tid * 8;
  const uint16_t* gL = Ytl + (size_t)b * 262144 + tid * 8;

  // fragment read offsets (byte, slot-local)
  const int aoff = (wr * 64 + lm) * 64 + g * 16;            // + fm*1024
  const int boff = (wc * 64 + lm) * 64 + g * 16;            // + fn*1024

  f32x4 acc[4][4] = {};

  // prologue: stage tiles 0,1 into slots 0,1
  STAGE(0, 0);
  STAGE(1, 40960);

  int csl = 0, ssl = 81920;   // compute-slot, stage-slot byte offsets
#pragma unroll 1
  for (int t = 0; t < 32; ++t) {
    if (t < 31) { asm volatile("s_waitcnt vmcnt(5)" ::: "memory"); }
    else        { asm volatile("s_waitcnt vmcnt(0)" ::: "memory"); }
    __builtin_amdgcn_s_barrier();
    __builtin_amdgcn_sched_barrier(0);
    if (t < 30) { STAGE(t + 2, ssl); }
    __builtin_amdgcn_sched_barrier(0);

    const uint8_t* sb = smem + csl;
    short8 af[4], hf[4], lf[4];
#pragma unroll
    for (int f = 0; f < 4; ++f) {
      af[f] = *(const short8*)(sb + aoff + f * 1024);
      hf[f] = *(const short8*)(sb + 8192 + boff + f * 1024);
      lf[f] = *(const short8*)(sb + 24576 + boff + f * 1024);
    }
    __builtin_amdgcn_s_setprio(1);
#pragma unroll
    for (int fm = 0; fm < 4; ++fm)
#pragma unroll
      for (int fn = 0; fn < 4; ++fn)
        acc[fm][fn] = mfma16(af[fm], hf[fn], acc[fm][fn]);
#pragma unroll
    for (int fm = 0; fm < 4; ++fm)
#pragma unroll
      for (int fn = 0; fn < 4; ++fn)
        acc[fm][fn] = mfma16(af[fm], lf[fn], acc[fm][fn]);
    __builtin_amdgcn_s_setprio(0);

    csl += 40960; if (csl == 122880) csl = 0;
    ssl += 40960; if (ssl == 122880) ssl = 0;
  }

  // epilogue: mask (per out-node), exact gelu, NT store (don't evict Y from L2)
  const float* mk_b = mask + b * 1024;
#pragma unroll
  for (int fm = 0; fm < 4; ++fm) {
    const int m = mb * 128 + wr * 64 + fm * 16 + g * 4;
    float mk[4];
#pragma unroll
    for (int e = 0; e < 4; ++e) mk[e] = mk_b[m + e];
#pragma unroll
    for (int fn = 0; fn < 4; ++fn) {
      const int n = wc * 64 + fn * 16 + lm;
#pragma unroll
      for (int e = 0; e < 4; ++e) {
        const float v = gelu_exact(acc[fm][fn][e] * mk[e]);
        const size_t o = ((size_t)(b * 1024 + m + e)) * 256 + n;
        if (LAST) {
          __builtin_nontemporal_store(v, &out[o]);
        } else {
          const uint16_t hb = f2bf(v);
          __builtin_nontemporal_store(hb, &Xh[o]);
          __builtin_nontemporal_store(f2bf(v - bf2f(hb)), &Xl[o]);
        }
      }
    }
  }
}

extern "C" void kernel_launch(void* const* d_in, const int* in_sizes, int n_in,
                              void* d_out, int out_size, void* d_ws, size_t ws_size,
                              hipStream_t stream) {
  const float* x    = (const float*)d_in[0];
  const float* mask = (const float*)d_in[1];
  const float* adj  = (const float*)d_in[2];
  const float* W[3]  = {(const float*)d_in[3], (const float*)d_in[5], (const float*)d_in[7]};
  const float* bs[3] = {(const float*)d_in[4], (const float*)d_in[6], (const float*)d_in[8]};

  uint8_t* ws = (uint8_t*)d_ws;
  uint16_t* An  = (uint16_t*)(ws);                    // 67108864 B (tiled)
  uint16_t* Xh  = (uint16_t*)(ws + 67108864);         // 16777216
  uint16_t* Xl  = (uint16_t*)(ws + 83886080);         // 16777216
  uint16_t* Yth = (uint16_t*)(ws + 100663296);        // 16777216 (tiled)
  uint16_t* Ytl = (uint16_t*)(ws + 117440512);        // 16777216 (tiled)
  uint16_t* Wh  = (uint16_t*)(ws + 134217728);        // 393216
  uint16_t* Wl  = (uint16_t*)(ws + 134610944);        // 393216

  k_split<<<dim3(8192), 256, 0, stream>>>(x, Xh, Xl, 2097152);
  for (int i = 0; i < 3; ++i)
    k_split<<<dim3(64), 256, 0, stream>>>(W[i], Wh + i * 65536, Wl + i * 65536, 16384);
  k_norm_adj<<<dim3(32768), 256, 0, stream>>>(adj, An);

  for (int l = 0; l < 3; ++l) {
    k_linear<<<dim3(256, 2), 256, 0, stream>>>(Xh, Xl, Wh + l * 65536, Wl + l * 65536,
                                               bs[l], Yth, Ytl);
    if (l < 2)
      k_agg<false><<<dim3(256), 512, 0, stream>>>(An, Yth, Ytl, mask, Xh, Xl, nullptr);
    else
      k_agg<true><<<dim3(256), 512, 0, stream>>>(An, Yth, Ytl, mask, nullptr, nullptr,
                                                 (float*)d_out);
  }
}

// Round 8
// 211.408 us; speedup vs baseline: 1.3449x; 1.3449x over previous
//
#include <hip/hip_runtime.h>
#include <stdint.h>

// GraphConvLayer: 3x { x = X@W^T + b; x = Ahat @ x; x *= mask; x = gelu(x) }
// B=32, N=1024, D=256. Split-bf16 (hi/lo) for linear; SINGLE-term aggregate.
// R8: revert all NT (R7 regression). k_agg drops the Y-lo term: tile bytes
//     40->24KB (-40%), per the empirical ~6.3 B/cyc/CU ingest law this is the
//     only lever that has moved k_agg. 4-slot LDS ring (96KB), depth-3
//     prefetch, counted vmcnt(6). Linear stays 3-term (Xh+Xl preserved).
// Tiled layouts (bf16, 16B-aligned):
//   An : [b][mb=node/128][kt=k/32][row 128][32]   tile stride 4096 elems
//   Yt : [b][kt=node/32][feat 256][32]            tile stride 8192 elems

typedef __attribute__((ext_vector_type(8))) short short8;   // 8 bf16 (4 VGPRs)
typedef __attribute__((ext_vector_type(4))) float f32x4;    // MFMA acc

__device__ __forceinline__ uint16_t f2bf(float f) {
  uint32_t u = __float_as_uint(f);
  u += 0x7FFF + ((u >> 16) & 1);          // RNE
  return (uint16_t)(u >> 16);
}
__device__ __forceinline__ float bf2f(uint16_t h) {
  return __uint_as_float(((uint32_t)h) << 16);
}
__device__ __forceinline__ float gelu_exact(float v) {
  return 0.5f * v * (1.0f + erff(v * 0.70710678118654752f));
}
__device__ __forceinline__ f32x4 mfma16(short8 a, short8 b, f32x4 c) {
  return __builtin_amdgcn_mfma_f32_16x16x32_bf16(a, b, c, 0, 0, 0);
}

#define GLD16(gsrc, ldst) __builtin_amdgcn_global_load_lds(                    \
    (const __attribute__((address_space(1))) void*)(gsrc),                     \
    (__attribute__((address_space(3))) void*)(ldst), 16, 0, 0)

// ---------------- split f32 -> bf16 hi/lo ----------------
__global__ void k_split(const float* __restrict__ src, uint16_t* __restrict__ h,
                        uint16_t* __restrict__ l, int n4) {
  int i = blockIdx.x * blockDim.x + threadIdx.x;
  if (i >= n4) return;
  const float4 v = ((const float4*)src)[i];
  float vv[4] = {v.x, v.y, v.z, v.w};
  ushort4 hh, ll;
  uint16_t* hp = (uint16_t*)&hh;
  uint16_t* lp = (uint16_t*)&ll;
#pragma unroll
  for (int e = 0; e < 4; ++e) {
    uint16_t hb = f2bf(vv[e]);
    hp[e] = hb;
    lp[e] = f2bf(vv[e] - bf2f(hb));
  }
  ((ushort4*)h)[i] = hh;
  ((ushort4*)l)[i] = ll;
}

// ---------------- row-normalize adj -> bf16, TILED store ----------------
__global__ void k_norm_adj(const float* __restrict__ adj, uint16_t* __restrict__ An) {
  const int r = blockIdx.x;       // 0..32767 = b*1024 + node
  const int t = threadIdx.x;      // 0..255, handles k = t*4 .. t*4+3
  const float* row = adj + (size_t)r * 1024;
  const float4 v = *(const float4*)(row + t * 4);
  float s = v.x + v.y + v.z + v.w;
#pragma unroll
  for (int off = 32; off; off >>= 1) s += __shfl_down(s, off);
  __shared__ float ws[4];
  if ((t & 63) == 0) ws[t >> 6] = s;
  __syncthreads();
  const float deg = ws[0] + ws[1] + ws[2] + ws[3];
  const float dinv = (deg != 0.f) ? 1.f / deg : 0.f;
  ushort4 o;
  uint16_t* op = (uint16_t*)&o;
  float vv[4] = {v.x, v.y, v.z, v.w};
#pragma unroll
  for (int e = 0; e < 4; ++e) op[e] = f2bf(vv[e] * dinv);
  // tiled: [b][mb][kt][row 128][32]
  const int b = r >> 10, node = r & 1023;
  const int mb = node >> 7, rr = node & 127;
  const int kt = t >> 3, ko = (t * 4) & 31;
  const size_t oo = (size_t)(b * 8 + mb) * 131072 + kt * 4096 + rr * 32 + ko;
  *(ushort4*)(An + oo) = o;
}

// ---------------- linear: Yt = (X @ W^T + b), 3-term, TILED hi-only store ----------------
__global__ __launch_bounds__(256) void k_linear(
    const uint16_t* __restrict__ Xh, const uint16_t* __restrict__ Xl,
    const uint16_t* __restrict__ Wh, const uint16_t* __restrict__ Wl,
    const float* __restrict__ bias,
    uint16_t* __restrict__ Yth) {
  __shared__ __align__(16) uint8_t smem[32768];  // Ah|Al|Wh|Wl tiles, 8KB each
  const int tid = threadIdx.x;
  const int lane = tid & 63;
  const int wave = tid >> 6;
  const int wr = wave >> 1, wc = wave & 1;
  const int m0 = blockIdx.x * 128;   // global row (b*1024+node)
  const int n0 = blockIdx.y * 128;   // out-feature
  const int lm = lane & 15, g = lane >> 4;
  const int srow = lane >> 2;
  const int skof = (lane & 3) * 8;

  f32x4 acc[4][4] = {};

  for (int kt = 0; kt < 8; ++kt) {
    const int k0 = kt * 32;
    __syncthreads();
#pragma unroll
    for (int j = 0; j < 8; ++j) {
      const int c = j * 4 + wave;    // 0..31
      const int sub = c & 7, which = c >> 3;
      const int row = sub * 16 + srow;
      const uint16_t* src;
      if (which == 0)      src = Xh + (size_t)(m0 + row) * 256 + k0 + skof;
      else if (which == 1) src = Xl + (size_t)(m0 + row) * 256 + k0 + skof;
      else if (which == 2) src = Wh + (size_t)(n0 + row) * 256 + k0 + skof;
      else                 src = Wl + (size_t)(n0 + row) * 256 + k0 + skof;
      GLD16(src, smem + c * 1024);
    }
    asm volatile("s_waitcnt vmcnt(0)" ::: "memory");
    __syncthreads();

    const uint8_t* Ahs = smem;
    const uint8_t* Als = smem + 8192;
    const uint8_t* Bhs = smem + 16384;
    const uint8_t* Bls = smem + 24576;
    short8 ah[4], al[4], bh[4], bl[4];
#pragma unroll
    for (int f = 0; f < 4; ++f) {
      ah[f] = *(const short8*)(Ahs + (wr * 64 + f * 16 + lm) * 64 + g * 16);
      al[f] = *(const short8*)(Als + (wr * 64 + f * 16 + lm) * 64 + g * 16);
      bh[f] = *(const short8*)(Bhs + (wc * 64 + f * 16 + lm) * 64 + g * 16);
      bl[f] = *(const short8*)(Bls + (wc * 64 + f * 16 + lm) * 64 + g * 16);
    }
#pragma unroll
    for (int fm = 0; fm < 4; ++fm)
#pragma unroll
      for (int fn = 0; fn < 4; ++fn) {
        acc[fm][fn] = mfma16(ah[fm], bh[fn], acc[fm][fn]);
        acc[fm][fn] = mfma16(ah[fm], bl[fn], acc[fm][fn]);
        acc[fm][fn] = mfma16(al[fm], bh[fn], acc[fm][fn]);
      }
  }

  // epilogue: +bias, store hi-only TILED [b][kt][feat][32]
#pragma unroll
  for (int fn = 0; fn < 4; ++fn) {
    const int n = n0 + wc * 64 + fn * 16 + lm;
    const float bv = bias[n];
#pragma unroll
    for (int fm = 0; fm < 4; ++fm) {
      const int mg = m0 + wr * 64 + fm * 16 + g * 4;
      const int bb = mg >> 10, node = mg & 1023;
      const int kt = node >> 5, ko = node & 31;
      ushort4 hh;
      uint16_t* hp = (uint16_t*)&hh;
#pragma unroll
      for (int e = 0; e < 4; ++e) hp[e] = f2bf(acc[fm][fn][e] + bv);
      const size_t o = ((size_t)(bb * 32 + kt) * 256 + n) * 32 + ko;
      *(ushort4*)(Yth + o) = hh;
    }
  }
}

// ---------------- aggregate: Z = An[b] @ Yh, mask, gelu ----------------
// Tile 128(M) x 256(N) x 32(K), 32 K-tiles. 8 waves (2M x 4N), wave 64x64.
// GLD-staged 4-slot LDS ring [A 8K | Yh 16K] = 24576B/slot, depth-3 prefetch,
// counted vmcnt(6). One raw s_barrier per tile; stage t+3 post-barrier.
#define STAGE(T, SSL) {                                                        \
    const size_t ta_ = (size_t)(T) * 4096;                                     \
    const size_t tb_ = (size_t)(T) * 8192;                                     \
    uint8_t* d_ = smem + (SSL) + wofs;                                         \
    GLD16(gA + ta_,        d_);                                                \
    GLD16(gH + tb_,        d_ + 8192);                                         \
    GLD16(gH + tb_ + 4096, d_ + 16384);                                        \
  }

template <bool LAST>
__global__ __launch_bounds__(512, 1) void k_agg(
    const uint16_t* __restrict__ An,
    const uint16_t* __restrict__ Yth,
    const float* __restrict__ mask,
    uint16_t* __restrict__ Xh, uint16_t* __restrict__ Xl,
    float* __restrict__ out) {
  __shared__ __align__(16) uint8_t smem[98304];   // 4 x 24576 ring
  const int tid = threadIdx.x;
  const int lane = tid & 63;
  const int wave = tid >> 6;            // 0..7
  const int wr = wave >> 2, wc = wave & 3;        // 2(M) x 4(N)
  const int id = blockIdx.x;            // 0..255
  const int swz = (id & 7) * 32 + (id >> 3);      // XCD-chunked (bijective)
  const int b = swz >> 3;               // batch
  const int mb = swz & 7;               // node block (of 128)
  const int lm = lane & 15, g = lane >> 4;
  const int wofs = wave * 1024;         // wave-uniform staging dst offset

  // per-thread staging sources (tiled layouts are GLD-linear)
  const uint16_t* gA = An  + (size_t)(b * 8 + mb) * 131072 + tid * 8;
  const uint16_t* gH = Yth + (size_t)b * 262144 + tid * 8;

  // fragment read offsets (byte, slot-local)
  const int aoff = (wr * 64 + lm) * 64 + g * 16;            // + fm*1024
  const int boff = (wc * 64 + lm) * 64 + g * 16;            // + fn*1024

  f32x4 acc[4][4] = {};

  // prologue: stage tiles 0,1,2 into slots 0,1,2
  STAGE(0, 0);
  STAGE(1, 24576);
  STAGE(2, 49152);

  int csl = 0, ssl = 73728;   // compute-slot, stage-slot byte offsets
#pragma unroll 1
  for (int t = 0; t < 32; ++t) {
    if (t <= 29)      { asm volatile("s_waitcnt vmcnt(6)" ::: "memory"); }
    else if (t == 30) { asm volatile("s_waitcnt vmcnt(3)" ::: "memory"); }
    else              { asm volatile("s_waitcnt vmcnt(0)" ::: "memory"); }
    __builtin_amdgcn_s_barrier();
    __builtin_amdgcn_sched_barrier(0);
    if (t < 29) { STAGE(t + 3, ssl); }
    __builtin_amdgcn_sched_barrier(0);

    const uint8_t* sb = smem + csl;
    short8 af[4], hf[4];
#pragma unroll
    for (int f = 0; f < 4; ++f) {
      af[f] = *(const short8*)(sb + aoff + f * 1024);
      hf[f] = *(const short8*)(sb + 8192 + boff + f * 1024);
    }
    __builtin_amdgcn_s_setprio(1);
#pragma unroll
    for (int fm = 0; fm < 4; ++fm)
#pragma unroll
      for (int fn = 0; fn < 4; ++fn)
        acc[fm][fn] = mfma16(af[fm], hf[fn], acc[fm][fn]);
    __builtin_amdgcn_s_setprio(0);

    csl += 24576; if (csl == 98304) csl = 0;
    ssl += 24576; if (ssl == 98304) ssl = 0;
  }

  // epilogue: mask (per out-node), exact gelu, store
  const float* mk_b = mask + b * 1024;
#pragma unroll
  for (int fm = 0; fm < 4; ++fm) {
    const int m = mb * 128 + wr * 64 + fm * 16 + g * 4;
    float mk[4];
#pragma unroll
    for (int e = 0; e < 4; ++e) mk[e] = mk_b[m + e];
#pragma unroll
    for (int fn = 0; fn < 4; ++fn) {
      const int n = wc * 64 + fn * 16 + lm;
#pragma unroll
      for (int e = 0; e < 4; ++e) {
        const float v = gelu_exact(acc[fm][fn][e] * mk[e]);
        const size_t o = ((size_t)(b * 1024 + m + e)) * 256 + n;
        if (LAST) {
          out[o] = v;
        } else {
          const uint16_t hb = f2bf(v);
          Xh[o] = hb;
          Xl[o] = f2bf(v - bf2f(hb));
        }
      }
    }
  }
}

extern "C" void kernel_launch(void* const* d_in, const int* in_sizes, int n_in,
                              void* d_out, int out_size, void* d_ws, size_t ws_size,
                              hipStream_t stream) {
  const float* x    = (const float*)d_in[0];
  const float* mask = (const float*)d_in[1];
  const float* adj  = (const float*)d_in[2];
  const float* W[3]  = {(const float*)d_in[3], (const float*)d_in[5], (const float*)d_in[7]};
  const float* bs[3] = {(const float*)d_in[4], (const float*)d_in[6], (const float*)d_in[8]};

  uint8_t* ws = (uint8_t*)d_ws;
  uint16_t* An  = (uint16_t*)(ws);                    // 67108864 B (tiled)
  uint16_t* Xh  = (uint16_t*)(ws + 67108864);         // 16777216
  uint16_t* Xl  = (uint16_t*)(ws + 83886080);         // 16777216
  uint16_t* Yth = (uint16_t*)(ws + 100663296);        // 16777216 (tiled)
  uint16_t* Wh  = (uint16_t*)(ws + 134217728);        // 393216
  uint16_t* Wl  = (uint16_t*)(ws + 134610944);        // 393216

  k_split<<<dim3(8192), 256, 0, stream>>>(x, Xh, Xl, 2097152);
  for (int i = 0; i < 3; ++i)
    k_split<<<dim3(64), 256, 0, stream>>>(W[i], Wh + i * 65536, Wl + i * 65536, 16384);
  k_norm_adj<<<dim3(32768), 256, 0, stream>>>(adj, An);

  for (int l = 0; l < 3; ++l) {
    k_linear<<<dim3(256, 2), 256, 0, stream>>>(Xh, Xl, Wh + l * 65536, Wl + l * 65536,
                                               bs[l], Yth);
    if (l < 2)
      k_agg<false><<<dim3(256), 512, 0, stream>>>(An, Yth, mask, Xh, Xl, nullptr);
    else
      k_agg<true><<<dim3(256), 512, 0, stream>>>(An, Yth, mask, nullptr, nullptr,
                                                 (float*)d_out);
  }
}